// Round 1
// baseline (409.024 us; speedup 1.0000x reference)
//
#include <hip/hip_runtime.h>

#define DMODEL 768
#define NTOK   512
#define BATCH  8
#define NHEAD  12
#define DK     64
#define NEGV   (-1e9f)

// ---------------------------------------------------------------------------
// Projection GEMM: out = X*W + b.  X:[4096x768], W:[768x768], row-major.
// 128x128 tile, BK=16, 256 threads, 8x8 microtile. blockIdx.z selects Q vs K.
// ---------------------------------------------------------------------------
__global__ __launch_bounds__(256)
void proj_kernel(const float* __restrict__ X,
                 const float* __restrict__ Wq, const float* __restrict__ bq,
                 const float* __restrict__ Wk, const float* __restrict__ bk,
                 float* __restrict__ Qout, float* __restrict__ Kout) {
    const int sel = blockIdx.z;
    const float* __restrict__ W    = sel ? Wk : Wq;
    const float* __restrict__ bias = sel ? bk : bq;
    float* __restrict__ out        = sel ? Kout : Qout;

    const int n0  = blockIdx.x * 128;
    const int m0  = blockIdx.y * 128;
    const int tid = threadIdx.x;
    const int tx  = tid & 15;   // n direction (8 cols each)
    const int ty  = tid >> 4;   // m direction (8 rows each)

    __shared__ float As[16][132];  // [k][m], padded
    __shared__ float Bs[16][132];  // [k][n], padded

    float acc[8][8];
    #pragma unroll
    for (int i = 0; i < 8; ++i)
        #pragma unroll
        for (int j = 0; j < 8; ++j) acc[i][j] = 0.f;

    for (int kt = 0; kt < DMODEL; kt += 16) {
        // A tile: 128 rows x 16 k = 512 float4
        #pragma unroll
        for (int i = 0; i < 2; ++i) {
            int fi = tid + i * 256;
            int row = fi >> 2, c4 = fi & 3;
            float4 a = *(const float4*)&X[(size_t)(m0 + row) * DMODEL + kt + c4 * 4];
            As[c4*4+0][row] = a.x; As[c4*4+1][row] = a.y;
            As[c4*4+2][row] = a.z; As[c4*4+3][row] = a.w;
        }
        // W tile: 16 k x 128 n = 512 float4
        #pragma unroll
        for (int i = 0; i < 2; ++i) {
            int fi = tid + i * 256;
            int kr = fi >> 5, n4 = fi & 31;
            float4 w = *(const float4*)&W[(size_t)(kt + kr) * DMODEL + n0 + n4 * 4];
            *(float4*)&Bs[kr][n4*4] = w;
        }
        __syncthreads();
        #pragma unroll
        for (int k = 0; k < 16; ++k) {
            float4 a0 = *(float4*)&As[k][ty*8];
            float4 a1 = *(float4*)&As[k][ty*8+4];
            float4 b0 = *(float4*)&Bs[k][tx*8];
            float4 b1 = *(float4*)&Bs[k][tx*8+4];
            float av[8] = {a0.x,a0.y,a0.z,a0.w,a1.x,a1.y,a1.z,a1.w};
            float bv[8] = {b0.x,b0.y,b0.z,b0.w,b1.x,b1.y,b1.z,b1.w};
            #pragma unroll
            for (int i = 0; i < 8; ++i)
                #pragma unroll
                for (int j = 0; j < 8; ++j)
                    acc[i][j] += av[i] * bv[j];
        }
        __syncthreads();
    }

    float4 bv0 = *(const float4*)&bias[n0 + tx*8];
    float4 bv1 = *(const float4*)&bias[n0 + tx*8 + 4];
    float bb[8] = {bv0.x,bv0.y,bv0.z,bv0.w,bv1.x,bv1.y,bv1.z,bv1.w};
    #pragma unroll
    for (int i = 0; i < 8; ++i) {
        size_t base = (size_t)(m0 + ty*8 + i) * DMODEL + n0 + tx*8;
        float4 r0 = { acc[i][0]+bb[0], acc[i][1]+bb[1], acc[i][2]+bb[2], acc[i][3]+bb[3] };
        float4 r1 = { acc[i][4]+bb[4], acc[i][5]+bb[5], acc[i][6]+bb[6], acc[i][7]+bb[7] };
        *(float4*)&out[base]     = r0;
        *(float4*)&out[base + 4] = r1;
    }
}

// ---------------------------------------------------------------------------
// Fused scores + blend + mask + softmax.
// One block = (b, h, 32 q rows). 256 threads = (tx 0..31) x (ty 0..7).
// Thread owns q rows ty*4..ty*4+3 and k cols {kt*128 + tx*4 + j} for all 4 kt.
// All 512 score columns per row live in registers (acc[4][16]); each q row is
// contained in one 32-lane group -> shfl-only softmax.
// ---------------------------------------------------------------------------
__global__ __launch_bounds__(256)
void attn_kernel(const float* __restrict__ Q, const float* __restrict__ K,
                 const float* __restrict__ dep, const int* __restrict__ mask,
                 float* __restrict__ out) {
    const int qt = blockIdx.x;   // 0..15
    const int h  = blockIdx.y;   // 0..11
    const int b  = blockIdx.z;   // 0..7
    const int tid = threadIdx.x;
    const int tx = tid & 31;
    const int ty = tid >> 5;

    __shared__ float Qs[DK][36];    // [d][q], padded
    __shared__ float Ks[DK][132];   // [d][k], padded

    // stage Q tile: 32 q x 64 d = 512 float4
    #pragma unroll
    for (int i = 0; i < 2; ++i) {
        int fi = tid + i * 256;
        int q = fi >> 4, d4 = fi & 15;
        float4 qv = *(const float4*)&Q[(size_t)(b*NTOK + qt*32 + q) * DMODEL + h*DK + d4*4];
        Qs[d4*4+0][q] = qv.x; Qs[d4*4+1][q] = qv.y;
        Qs[d4*4+2][q] = qv.z; Qs[d4*4+3][q] = qv.w;
    }

    float acc[4][16];
    #pragma unroll
    for (int i = 0; i < 4; ++i)
        #pragma unroll
        for (int j = 0; j < 16; ++j) acc[i][j] = 0.f;

    for (int kt = 0; kt < 4; ++kt) {
        __syncthreads();
        // stage K tile: 128 k x 64 d = 2048 float4
        #pragma unroll
        for (int i = 0; i < 8; ++i) {
            int fi = tid + i * 256;
            int kk = fi >> 4, d4 = fi & 15;
            float4 kv = *(const float4*)&K[(size_t)(b*NTOK + kt*128 + kk) * DMODEL + h*DK + d4*4];
            Ks[d4*4+0][kk] = kv.x; Ks[d4*4+1][kk] = kv.y;
            Ks[d4*4+2][kk] = kv.z; Ks[d4*4+3][kk] = kv.w;
        }
        __syncthreads();
        #pragma unroll
        for (int d = 0; d < DK; ++d) {
            float4 q4 = *(float4*)&Qs[d][ty*4];
            float4 k4 = *(float4*)&Ks[d][tx*4];
            float qv[4] = {q4.x,q4.y,q4.z,q4.w};
            float kv[4] = {k4.x,k4.y,k4.z,k4.w};
            #pragma unroll
            for (int i = 0; i < 4; ++i)
                #pragma unroll
                for (int j = 0; j < 4; ++j)
                    acc[i][kt*4+j] += qv[i] * kv[j];
        }
    }

    // blend with dep bias + mask
    const float scale = (1.0f - 0.1f) / 8.0f;   // (1-d_weight)/sqrt(dk)
    #pragma unroll
    for (int kt = 0; kt < 4; ++kt) {
        const int kg = kt*128 + tx*4;
        const int4 mv = *(const int4*)&mask[b*NTOK + kg];
        #pragma unroll
        for (int i = 0; i < 4; ++i) {
            const int q = qt*32 + ty*4 + i;
            float4 dv = *(const float4*)&dep[((size_t)b*NTOK + q) * NTOK + kg];
            float* a = &acc[i][kt*4];
            a[0] = mv.x ? scale*a[0] + 0.1f*dv.x : NEGV;
            a[1] = mv.y ? scale*a[1] + 0.1f*dv.y : NEGV;
            a[2] = mv.z ? scale*a[2] + 0.1f*dv.z : NEGV;
            a[3] = mv.w ? scale*a[3] + 0.1f*dv.w : NEGV;
        }
    }

    // softmax per q row: row lives in 32 lanes (same ty) x 16 regs
    float inv_l[4];
    #pragma unroll
    for (int i = 0; i < 4; ++i) {
        float m = NEGV;
        #pragma unroll
        for (int j = 0; j < 16; ++j) m = fmaxf(m, acc[i][j]);
        #pragma unroll
        for (int off = 16; off >= 1; off >>= 1)
            m = fmaxf(m, __shfl_xor(m, off));
        float l = 0.f;
        #pragma unroll
        for (int j = 0; j < 16; ++j) {
            float e = __expf(acc[i][j] - m);
            acc[i][j] = e;
            l += e;
        }
        #pragma unroll
        for (int off = 16; off >= 1; off >>= 1)
            l += __shfl_xor(l, off);
        inv_l[i] = 1.0f / l;
    }

    // coalesced float4 writes
    #pragma unroll
    for (int i = 0; i < 4; ++i) {
        const int q = qt*32 + ty*4 + i;
        size_t rowbase = ((size_t)(b*NHEAD + h) * NTOK + q) * NTOK;
        #pragma unroll
        for (int kt = 0; kt < 4; ++kt) {
            float4 p = { acc[i][kt*4+0]*inv_l[i], acc[i][kt*4+1]*inv_l[i],
                         acc[i][kt*4+2]*inv_l[i], acc[i][kt*4+3]*inv_l[i] };
            *(float4*)&out[rowbase + kt*128 + tx*4] = p;
        }
    }
}

extern "C" void kernel_launch(void* const* d_in, const int* in_sizes, int n_in,
                              void* d_out, int out_size, void* d_ws, size_t ws_size,
                              hipStream_t stream) {
    const float* X    = (const float*)d_in[0];
    const int*   mask = (const int*)  d_in[1];
    const float* dep  = (const float*)d_in[2];
    const float* Wq   = (const float*)d_in[3];
    const float* bq   = (const float*)d_in[4];
    const float* Wk   = (const float*)d_in[5];
    const float* bk   = (const float*)d_in[6];
    float* out = (float*)d_out;

    float* Qbuf = (float*)d_ws;
    float* Kbuf = Qbuf + (size_t)BATCH * NTOK * DMODEL;

    dim3 pg(DMODEL/128, (BATCH*NTOK)/128, 2);   // (6, 32, 2)
    proj_kernel<<<pg, 256, 0, stream>>>(X, Wq, bq, Wk, bk, Qbuf, Kbuf);

    dim3 ag(NTOK/32, NHEAD, BATCH);             // (16, 12, 8)
    attn_kernel<<<ag, 256, 0, stream>>>(Qbuf, Kbuf, dep, mask, out);
}

// Round 2
// 206.858 us; speedup vs baseline: 1.9773x; 1.9773x over previous
//
#include <hip/hip_runtime.h>

// R2: full f16-MFMA rewrite.
//   convert_x:   X fp32 -> Xh f16
//   transpose_w: Wq,Wk fp32 [k][n] -> Wt f16 [n][k] (rows 0-767 Wq^T, 768-1535 Wk^T)
//   proj_mfma:   QK[4096][1536] f16 = Xh*Wt^T + bias  (cols 0-767 Q, 768-1535 K)
//   attn_mfma:   per-wave 16 q-rows x 512 cols, MFMA scores + blend + mask + softmax
// No LDS in the GEMMs: operand fragments read straight from global (L2-resident,
// total operand traffic ~300 MB at 34 TB/s -> ~10 us; avoids staging latency/barriers).

typedef _Float16 f16;
typedef _Float16 f16x4 __attribute__((ext_vector_type(4)));
typedef _Float16 f16x8 __attribute__((ext_vector_type(8)));
typedef float    f32x4 __attribute__((ext_vector_type(4)));

#define NTOK   512
#define DMODEL 768
#define BATCH  8
#define NHEAD  12
#define NEGV   (-1e9f)

// ---------------------------------------------------------------------------
__global__ __launch_bounds__(256)
void convert_x(const float* __restrict__ X, f16* __restrict__ Xh) {
    const size_t i = ((size_t)blockIdx.x * 256 + threadIdx.x) * 4;
    float4 v = *(const float4*)&X[i];
    f16x4 h = { (f16)v.x, (f16)v.y, (f16)v.z, (f16)v.w };
    *(f16x4*)&Xh[i] = h;
}

// ---------------------------------------------------------------------------
// Wt[n][k] = W[k][n], f16. grid (24 k-tiles, 48 n-tiles), block (32,8).
__global__ __launch_bounds__(256)
void transpose_w(const float* __restrict__ Wq, const float* __restrict__ Wk,
                 f16* __restrict__ Wt) {
    __shared__ float tile[32][33];
    const int kb = blockIdx.x * 32;
    const int nb = blockIdx.y * 32;           // combined n in [0,1536)
    const float* __restrict__ W = (nb < 768) ? Wq : Wk;
    const int nc = (nb < 768) ? nb : nb - 768;
    const int tx = threadIdx.x, ty = threadIdx.y;
    #pragma unroll
    for (int i = 0; i < 4; ++i)
        tile[ty + i*8][tx] = W[(size_t)(kb + ty + i*8) * DMODEL + nc + tx];
    __syncthreads();
    #pragma unroll
    for (int i = 0; i < 4; ++i)
        Wt[(size_t)(nb + ty + i*8) * DMODEL + kb + tx] = (f16)tile[tx][ty + i*8];
}

// ---------------------------------------------------------------------------
// proj: one wave per 64x64 output tile. grid (64, 24), block 64.
__global__ __launch_bounds__(64)
void proj_mfma(const f16* __restrict__ Xh, const f16* __restrict__ Wt,
               const float* __restrict__ bq, const float* __restrict__ bk,
               f16* __restrict__ QK) {
    const int m0 = blockIdx.x * 64;
    const int n0 = blockIdx.y * 64;
    const int l = threadIdx.x;
    const int l15 = l & 15, quad = l >> 4;

    f32x4 acc[4][4];
    #pragma unroll
    for (int i = 0; i < 4; ++i)
        #pragma unroll
        for (int j = 0; j < 4; ++j) acc[i][j] = (f32x4){0.f, 0.f, 0.f, 0.f};

    const f16* __restrict__ Ab = Xh + (size_t)(m0 + l15) * DMODEL + quad * 8;
    const f16* __restrict__ Bb = Wt + (size_t)(n0 + l15) * DMODEL + quad * 8;

    for (int ks = 0; ks < DMODEL / 32; ++ks) {
        f16x8 a[4], b[4];
        #pragma unroll
        for (int mi = 0; mi < 4; ++mi)
            a[mi] = *(const f16x8*)(Ab + (size_t)mi * 16 * DMODEL + ks * 32);
        #pragma unroll
        for (int ni = 0; ni < 4; ++ni)
            b[ni] = *(const f16x8*)(Bb + (size_t)ni * 16 * DMODEL + ks * 32);
        #pragma unroll
        for (int mi = 0; mi < 4; ++mi)
            #pragma unroll
            for (int ni = 0; ni < 4; ++ni)
                acc[mi][ni] = __builtin_amdgcn_mfma_f32_16x16x32_f16(
                    a[mi], b[ni], acc[mi][ni], 0, 0, 0);
    }

    const float* __restrict__ bias = (n0 < 768) ? (bq + n0) : (bk + n0 - 768);
    #pragma unroll
    for (int ni = 0; ni < 4; ++ni) {
        const float bv = bias[ni * 16 + l15];
        const int col = n0 + ni * 16 + l15;
        #pragma unroll
        for (int mi = 0; mi < 4; ++mi) {
            #pragma unroll
            for (int r = 0; r < 4; ++r) {
                const int row = m0 + mi * 16 + quad * 4 + r;
                QK[(size_t)row * 1536 + col] = (f16)(acc[mi][ni][r] + bv);
            }
        }
    }
}

// ---------------------------------------------------------------------------
// attn: one wave = 16 q-rows x 512 k-cols for one (b,h). grid (32,12,8), block 64.
__global__ __launch_bounds__(64)
void attn_mfma(const f16* __restrict__ QK, const float* __restrict__ dep,
               const int* __restrict__ mask, float* __restrict__ out) {
    const int qt = blockIdx.x, h = blockIdx.y, b = blockIdx.z;
    const int l = threadIdx.x;
    const int l15 = l & 15, quad = l >> 4;
    const int q0 = qt * 16;

    f32x4 acc[32];
    #pragma unroll
    for (int t = 0; t < 32; ++t) acc[t] = (f32x4){0.f, 0.f, 0.f, 0.f};

    const f16* __restrict__ Qb = QK + (size_t)(b * NTOK + q0 + l15) * 1536 + h * 64 + quad * 8;
    const f16* __restrict__ Kb = QK + (size_t)(b * NTOK + l15) * 1536 + 768 + h * 64 + quad * 8;

    #pragma unroll
    for (int ks = 0; ks < 2; ++ks) {
        f16x8 a = *(const f16x8*)(Qb + ks * 32);
        #pragma unroll
        for (int t = 0; t < 32; ++t) {
            f16x8 bf = *(const f16x8*)(Kb + (size_t)t * 16 * 1536 + ks * 32);
            acc[t] = __builtin_amdgcn_mfma_f32_16x16x32_f16(a, bf, acc[t], 0, 0, 0);
        }
    }

    // blend with dep bias + mask
    const float SC = (1.0f - 0.1f) / 8.0f;   // (1-d_weight)/sqrt(dk)
    const float DW = 0.1f;
    const float* __restrict__ deprow = dep + ((size_t)b * NTOK + q0 + quad * 4) * NTOK;
    const int*   __restrict__ mrow   = mask + b * NTOK;
    #pragma unroll
    for (int t = 0; t < 32; ++t) {
        const int col = t * 16 + l15;
        const int mv = mrow[col];
        #pragma unroll
        for (int r = 0; r < 4; ++r) {
            const float dv = deprow[(size_t)r * NTOK + col];
            const float s = SC * acc[t][r] + DW * dv;
            acc[t][r] = mv ? s : NEGV;
        }
    }

    // softmax: each q-row lives in 16 lanes (fixed quad) x 32 regs
    float rmax[4] = {NEGV, NEGV, NEGV, NEGV};
    #pragma unroll
    for (int t = 0; t < 32; ++t)
        #pragma unroll
        for (int r = 0; r < 4; ++r) rmax[r] = fmaxf(rmax[r], acc[t][r]);
    #pragma unroll
    for (int r = 0; r < 4; ++r) {
        rmax[r] = fmaxf(rmax[r], __shfl_xor(rmax[r], 1));
        rmax[r] = fmaxf(rmax[r], __shfl_xor(rmax[r], 2));
        rmax[r] = fmaxf(rmax[r], __shfl_xor(rmax[r], 4));
        rmax[r] = fmaxf(rmax[r], __shfl_xor(rmax[r], 8));
    }
    float rsum[4] = {0.f, 0.f, 0.f, 0.f};
    #pragma unroll
    for (int t = 0; t < 32; ++t)
        #pragma unroll
        for (int r = 0; r < 4; ++r) {
            const float e = __expf(acc[t][r] - rmax[r]);
            acc[t][r] = e;
            rsum[r] += e;
        }
    #pragma unroll
    for (int r = 0; r < 4; ++r) {
        rsum[r] += __shfl_xor(rsum[r], 1);
        rsum[r] += __shfl_xor(rsum[r], 2);
        rsum[r] += __shfl_xor(rsum[r], 4);
        rsum[r] += __shfl_xor(rsum[r], 8);
    }
    float inv[4];
    #pragma unroll
    for (int r = 0; r < 4; ++r) inv[r] = 1.0f / rsum[r];

    float* __restrict__ orow = out + ((size_t)((b * NHEAD + h) * NTOK) + q0 + quad * 4) * NTOK;
    #pragma unroll
    for (int t = 0; t < 32; ++t)
        #pragma unroll
        for (int r = 0; r < 4; ++r)
            orow[(size_t)r * NTOK + t * 16 + l15] = acc[t][r] * inv[r];
}

// ---------------------------------------------------------------------------
extern "C" void kernel_launch(void* const* d_in, const int* in_sizes, int n_in,
                              void* d_out, int out_size, void* d_ws, size_t ws_size,
                              hipStream_t stream) {
    const float* X    = (const float*)d_in[0];
    const int*   mask = (const int*)  d_in[1];
    const float* dep  = (const float*)d_in[2];
    const float* Wq   = (const float*)d_in[3];
    const float* bq   = (const float*)d_in[4];
    const float* Wk   = (const float*)d_in[5];
    const float* bk   = (const float*)d_in[6];
    float* out = (float*)d_out;

    f16* Xh = (f16*)d_ws;                                  // 4096*768
    f16* Wt = Xh + (size_t)BATCH * NTOK * DMODEL;          // 1536*768
    f16* QK = Wt + (size_t)1536 * DMODEL;                  // 4096*1536

    convert_x<<<dim3((BATCH * NTOK * DMODEL) / (256 * 4)), 256, 0, stream>>>(X, Xh);
    transpose_w<<<dim3(DMODEL / 32, 1536 / 32), dim3(32, 8), 0, stream>>>(Wq, Wk, Wt);
    proj_mfma<<<dim3((BATCH * NTOK) / 64, 1536 / 64), 64, 0, stream>>>(Xh, Wt, bq, bk, QK);
    attn_mfma<<<dim3(NTOK / 16, NHEAD, BATCH), 64, 0, stream>>>(QK, dep, mask, out);
}

// Round 3
// 191.499 us; speedup vs baseline: 2.1359x; 1.0802x over previous
//
#include <hip/hip_runtime.h>

// R3: prep (convert X->f16 + transpose W->f16) fused; proj as R2 (per-wave
// 64x64 MFMA tile, direct global operands); attn restructured: 4-wave blocks,
// K-head staged in LDS (padded stride 72 halfs -> conflict-free b128 reads).

typedef _Float16 f16;
typedef _Float16 f16x4 __attribute__((ext_vector_type(4)));
typedef _Float16 f16x8 __attribute__((ext_vector_type(8)));
typedef float    f32x4 __attribute__((ext_vector_type(4)));

#define NTOK   512
#define DMODEL 768
#define BATCH  8
#define NHEAD  12
#define NEGV   (-1e9f)
#define KPAD   72   // LDS row stride in halfs (144 B, 16B-aligned, 2-way banks)

// ---------------------------------------------------------------------------
// prep: blocks [0,3072) convert X fp32->f16 (f32x4->f16x4 per thread);
//       blocks [3072,4224) transpose Wq/Wk 32x32 tiles -> Wt[n][k] f16.
__global__ __launch_bounds__(256)
void prep_kernel(const float* __restrict__ X, f16* __restrict__ Xh,
                 const float* __restrict__ Wq, const float* __restrict__ Wk,
                 f16* __restrict__ Wt) {
    const int bx = blockIdx.x;
    if (bx < 3072) {
        const size_t i = ((size_t)bx * 256 + threadIdx.x) * 4;
        float4 v = *(const float4*)&X[i];
        f16x4 h = { (f16)v.x, (f16)v.y, (f16)v.z, (f16)v.w };
        *(f16x4*)&Xh[i] = h;
    } else {
        __shared__ float tile[32][33];
        const int id = bx - 3072;
        const int kb = (id % 24) * 32;
        const int nb = (id / 24) * 32;          // combined n in [0,1536)
        const float* __restrict__ W = (nb < 768) ? Wq : Wk;
        const int nc = (nb < 768) ? nb : nb - 768;
        const int tx = threadIdx.x & 31, ty = threadIdx.x >> 5;
        #pragma unroll
        for (int i = 0; i < 4; ++i)
            tile[ty + i*8][tx] = W[(size_t)(kb + ty + i*8) * DMODEL + nc + tx];
        __syncthreads();
        #pragma unroll
        for (int i = 0; i < 4; ++i)
            Wt[(size_t)(nb + ty + i*8) * DMODEL + kb + tx] = (f16)tile[tx][ty + i*8];
    }
}

// ---------------------------------------------------------------------------
// proj: one wave per 64x64 output tile of QK[4096][1536]. grid (64,24), block 64.
__global__ __launch_bounds__(64)
void proj_mfma(const f16* __restrict__ Xh, const f16* __restrict__ Wt,
               const float* __restrict__ bq, const float* __restrict__ bk,
               f16* __restrict__ QK) {
    const int m0 = blockIdx.x * 64;
    const int n0 = blockIdx.y * 64;
    const int l = threadIdx.x;
    const int l15 = l & 15, quad = l >> 4;

    f32x4 acc[4][4];
    #pragma unroll
    for (int i = 0; i < 4; ++i)
        #pragma unroll
        for (int j = 0; j < 4; ++j) acc[i][j] = (f32x4){0.f, 0.f, 0.f, 0.f};

    const f16* __restrict__ Ab = Xh + (size_t)(m0 + l15) * DMODEL + quad * 8;
    const f16* __restrict__ Bb = Wt + (size_t)(n0 + l15) * DMODEL + quad * 8;

    for (int ks = 0; ks < DMODEL / 32; ++ks) {
        f16x8 a[4], b[4];
        #pragma unroll
        for (int mi = 0; mi < 4; ++mi)
            a[mi] = *(const f16x8*)(Ab + (size_t)mi * 16 * DMODEL + ks * 32);
        #pragma unroll
        for (int ni = 0; ni < 4; ++ni)
            b[ni] = *(const f16x8*)(Bb + (size_t)ni * 16 * DMODEL + ks * 32);
        #pragma unroll
        for (int mi = 0; mi < 4; ++mi)
            #pragma unroll
            for (int ni = 0; ni < 4; ++ni)
                acc[mi][ni] = __builtin_amdgcn_mfma_f32_16x16x32_f16(
                    a[mi], b[ni], acc[mi][ni], 0, 0, 0);
    }

    const float* __restrict__ bias = (n0 < 768) ? (bq + n0) : (bk + n0 - 768);
    #pragma unroll
    for (int ni = 0; ni < 4; ++ni) {
        const float bv = bias[ni * 16 + l15];
        const int col = n0 + ni * 16 + l15;
        #pragma unroll
        for (int mi = 0; mi < 4; ++mi)
            #pragma unroll
            for (int r = 0; r < 4; ++r) {
                const int row = m0 + mi * 16 + quad * 4 + r;
                QK[(size_t)row * 1536 + col] = (f16)(acc[mi][ni][r] + bv);
            }
    }
}

// ---------------------------------------------------------------------------
// attn: block = 4 waves = 64 q rows of one (b,h). K-head staged in LDS.
// grid (8,12,8), block 256.
__global__ __launch_bounds__(256, 2)
void attn_mfma(const f16* __restrict__ QK, const float* __restrict__ dep,
               const int* __restrict__ mask, float* __restrict__ out) {
    const int qt = blockIdx.x, h = blockIdx.y, b = blockIdx.z;
    const int tid = threadIdx.x;
    const int wid = tid >> 6;
    const int l = tid & 63;
    const int l15 = l & 15, quad = l >> 4;
    const int q0 = qt * 64 + wid * 16;

    __shared__ f16 Ks[NTOK * KPAD];   // 512 tokens x 72 halfs = 72 KB

    // stage K-head: 512 tokens x 8 chunks of f16x8; 16 chunks per thread
    {
        const f16* __restrict__ Ksrc = QK + (size_t)b * NTOK * 1536 + 768 + h * 64;
        #pragma unroll
        for (int c = 0; c < 16; ++c) {
            const int chunk = tid + c * 256;
            const int token = chunk >> 3;
            const int part  = chunk & 7;
            f16x8 v = *(const f16x8*)(Ksrc + (size_t)token * 1536 + part * 8);
            *(f16x8*)&Ks[token * KPAD + part * 8] = v;
        }
    }
    __syncthreads();

    f32x4 acc[32];
    #pragma unroll
    for (int t = 0; t < 32; ++t) acc[t] = (f32x4){0.f, 0.f, 0.f, 0.f};

    const f16* __restrict__ Qb = QK + (size_t)(b * NTOK + q0 + l15) * 1536 + h * 64 + quad * 8;

    #pragma unroll
    for (int ks = 0; ks < 2; ++ks) {
        f16x8 a = *(const f16x8*)(Qb + ks * 32);
        #pragma unroll
        for (int t = 0; t < 32; ++t) {
            f16x8 bf = *(const f16x8*)&Ks[(t * 16 + l15) * KPAD + ks * 32 + quad * 8];
            acc[t] = __builtin_amdgcn_mfma_f32_16x16x32_f16(a, bf, acc[t], 0, 0, 0);
        }
    }

    // blend with dep bias + mask
    const float SC = (1.0f - 0.1f) / 8.0f;   // (1-d_weight)/sqrt(dk)
    const float DW = 0.1f;
    const float* __restrict__ deprow = dep + ((size_t)b * NTOK + q0 + quad * 4) * NTOK;
    const int*   __restrict__ mrow   = mask + b * NTOK;
    #pragma unroll
    for (int t = 0; t < 32; ++t) {
        const int col = t * 16 + l15;
        const int mv = mrow[col];
        #pragma unroll
        for (int r = 0; r < 4; ++r) {
            const float dv = deprow[(size_t)r * NTOK + col];
            const float s = SC * acc[t][r] + DW * dv;
            acc[t][r] = mv ? s : NEGV;
        }
    }

    // softmax: each q-row lives in 16 lanes (fixed quad) x 32 regs
    float rmax[4] = {NEGV, NEGV, NEGV, NEGV};
    #pragma unroll
    for (int t = 0; t < 32; ++t)
        #pragma unroll
        for (int r = 0; r < 4; ++r) rmax[r] = fmaxf(rmax[r], acc[t][r]);
    #pragma unroll
    for (int r = 0; r < 4; ++r) {
        rmax[r] = fmaxf(rmax[r], __shfl_xor(rmax[r], 1));
        rmax[r] = fmaxf(rmax[r], __shfl_xor(rmax[r], 2));
        rmax[r] = fmaxf(rmax[r], __shfl_xor(rmax[r], 4));
        rmax[r] = fmaxf(rmax[r], __shfl_xor(rmax[r], 8));
    }
    float rsum[4] = {0.f, 0.f, 0.f, 0.f};
    #pragma unroll
    for (int t = 0; t < 32; ++t)
        #pragma unroll
        for (int r = 0; r < 4; ++r) {
            const float e = __expf(acc[t][r] - rmax[r]);
            acc[t][r] = e;
            rsum[r] += e;
        }
    #pragma unroll
    for (int r = 0; r < 4; ++r) {
        rsum[r] += __shfl_xor(rsum[r], 1);
        rsum[r] += __shfl_xor(rsum[r], 2);
        rsum[r] += __shfl_xor(rsum[r], 4);
        rsum[r] += __shfl_xor(rsum[r], 8);
    }
    float inv[4];
    #pragma unroll
    for (int r = 0; r < 4; ++r) inv[r] = 1.0f / rsum[r];

    float* __restrict__ orow = out + ((size_t)((b * NHEAD + h) * NTOK) + q0 + quad * 4) * NTOK;
    #pragma unroll
    for (int t = 0; t < 32; ++t)
        #pragma unroll
        for (int r = 0; r < 4; ++r)
            orow[(size_t)r * NTOK + t * 16 + l15] = acc[t][r] * inv[r];
}

// ---------------------------------------------------------------------------
extern "C" void kernel_launch(void* const* d_in, const int* in_sizes, int n_in,
                              void* d_out, int out_size, void* d_ws, size_t ws_size,
                              hipStream_t stream) {
    const float* X    = (const float*)d_in[0];
    const int*   mask = (const int*)  d_in[1];
    const float* dep  = (const float*)d_in[2];
    const float* Wq   = (const float*)d_in[3];
    const float* bq   = (const float*)d_in[4];
    const float* Wk   = (const float*)d_in[5];
    const float* bk   = (const float*)d_in[6];
    float* out = (float*)d_out;

    f16* Xh = (f16*)d_ws;                                  // 4096*768
    f16* Wt = Xh + (size_t)BATCH * NTOK * DMODEL;          // 1536*768
    f16* QK = Wt + (size_t)1536 * DMODEL;                  // 4096*1536

    prep_kernel<<<dim3(3072 + 1152), 256, 0, stream>>>(X, Xh, Wq, Wk, Wt);
    proj_mfma<<<dim3((BATCH * NTOK) / 64, 1536 / 64), 64, 0, stream>>>(Xh, Wt, bq, bk, QK);
    attn_mfma<<<dim3(NTOK / 64, NHEAD, BATCH), 256, 0, stream>>>(QK, dep, mask, out);
}